// Round 17
// baseline (570.702 us; speedup 1.0000x reference)
//
#include <hip/hip_runtime.h>

// ---------- small helpers ----------
typedef __attribute__((ext_vector_type(8))) short bf16x8;
typedef __attribute__((ext_vector_type(4))) float f32x4;
typedef __attribute__((ext_vector_type(2))) float f32x2;
typedef __attribute__((ext_vector_type(4))) unsigned int u32x4;

__device__ __forceinline__ unsigned short f2bf(float x) {
  union { float f; unsigned u; } v; v.f = x;
  unsigned r = v.u + 0x7fffu + ((v.u >> 16) & 1u);
  return (unsigned short)(r >> 16);
}
__device__ __forceinline__ float bf2f(unsigned short s) {
  union { unsigned u; float f; } v; v.u = ((unsigned)s) << 16;
  return v.f;
}
__device__ __forceinline__ float sigm(float x) { return 1.f / (1.f + __expf(-x)); }
__device__ __forceinline__ float tanh_fast(float x) { return 2.f * sigm(2.f * x) - 1.f; }

typedef const __attribute__((address_space(1))) void gvoid_t;
typedef __attribute__((address_space(3))) void lvoid_t;
__device__ __forceinline__ void gl16(const void* g, void* l) {
  __builtin_amdgcn_global_load_lds((gvoid_t*)g, (lvoid_t*)l, 16, 0, 0);
}

// 16 pipelined PLAIN sc1 loads (L3-fresh) in ONE asm block w/ internal wait.
__device__ __forceinline__ void ldh16_sc1(const unsigned short* p, u32x4 o[16]) {
  asm volatile(
      "global_load_dwordx4 %0, %16, off sc1\n\t"
      "global_load_dwordx4 %1, %16, off offset:64 sc1\n\t"
      "global_load_dwordx4 %2, %16, off offset:128 sc1\n\t"
      "global_load_dwordx4 %3, %16, off offset:192 sc1\n\t"
      "global_load_dwordx4 %4, %16, off offset:256 sc1\n\t"
      "global_load_dwordx4 %5, %16, off offset:320 sc1\n\t"
      "global_load_dwordx4 %6, %16, off offset:384 sc1\n\t"
      "global_load_dwordx4 %7, %16, off offset:448 sc1\n\t"
      "global_load_dwordx4 %8, %16, off offset:512 sc1\n\t"
      "global_load_dwordx4 %9, %16, off offset:576 sc1\n\t"
      "global_load_dwordx4 %10, %16, off offset:640 sc1\n\t"
      "global_load_dwordx4 %11, %16, off offset:704 sc1\n\t"
      "global_load_dwordx4 %12, %16, off offset:768 sc1\n\t"
      "global_load_dwordx4 %13, %16, off offset:832 sc1\n\t"
      "global_load_dwordx4 %14, %16, off offset:896 sc1\n\t"
      "global_load_dwordx4 %15, %16, off offset:960 sc1\n\t"
      "s_waitcnt vmcnt(0)"
      : "=&v"(o[0]), "=&v"(o[1]), "=&v"(o[2]), "=&v"(o[3]), "=&v"(o[4]),
        "=&v"(o[5]), "=&v"(o[6]), "=&v"(o[7]), "=&v"(o[8]), "=&v"(o[9]),
        "=&v"(o[10]), "=&v"(o[11]), "=&v"(o[12]), "=&v"(o[13]), "=&v"(o[14]),
        "=&v"(o[15])
      : "v"(p)
      : "memory");
}
__device__ __forceinline__ void st2_sc1(unsigned* p, unsigned v0, unsigned v1) {
  asm volatile("global_store_dword %0, %1, off sc1\n\t"
               "global_store_dword %0, %2, off offset:1024 sc1" ::"v"(p), "v"(v0),
               "v"(v1) : "memory");
}
// ISSUE-ONLY: 4 PGT loads + 1 mcnt probe, NO internal wait (fenced by next
// ldh16's vmcnt(0) + volatile "+v" dummy — rule #18 discipline).
__device__ __forceinline__ void ldpgt_issue(const unsigned short* p0,
                                            const unsigned short* p1,
                                            const unsigned short* p2,
                                            const unsigned short* p3, const int* pm,
                                            unsigned& o0, unsigned& o1, unsigned& o2,
                                            unsigned& o3, int& om) {
  asm volatile(
      "global_load_dword %0, %5, off sc1\n\t"
      "global_load_dword %1, %6, off sc1\n\t"
      "global_load_dword %2, %7, off sc1\n\t"
      "global_load_dword %3, %8, off sc1\n\t"
      "global_load_dword %4, %9, off sc1"
      : "=&v"(o0), "=&v"(o1), "=&v"(o2), "=&v"(o3), "=&v"(om)
      : "v"(p0), "v"(p1), "v"(p2), "v"(p3), "v"(pm)
      : "memory");
}
__device__ __forceinline__ void sts_sc1(unsigned short* p, unsigned short v) {
  asm volatile("global_store_short %0, %1, off sc1" ::"v"(p), "v"((unsigned)v)
               : "memory");
}

#define B_ 64
#define TDEC 63
#define D_ 512
#define V_ 10000
#define NWG 32
#define NCONS 223
#define NTILE_N 79
#define NTILE_M 32

// ---------- kernel 1: prep ----------
__global__ __launch_bounds__(256) void prep(
    const float* __restrict__ enc,
    const float* __restrict__ Wh0, const float* __restrict__ Wc0,
    const float* __restrict__ Wih, const float* __restrict__ Whh,
    const float* __restrict__ emb, const int* __restrict__ caps,
    short* __restrict__ Wcat, short* __restrict__ Wihe, short* __restrict__ Whhb,
    short* __restrict__ Xemb, unsigned short* __restrict__ Hall,
    unsigned short* __restrict__ App) {
  if (blockIdx.x < 128) {
    int b = blockIdx.x >> 1;
    int d = (blockIdx.x & 1) * 256 + threadIdx.x;
    const float* p = enc + (long)b * 196 * 512 + d;
    float s = 0.f;
#pragma unroll 4
    for (int i = 0; i < 196; ++i) s += p[(long)i * 512];
    unsigned short hi = f2bf(s);
    unsigned short lo = f2bf(s - bf2f(hi));
    App[b * 1536 + d] = hi;
    App[b * 1536 + 512 + d] = hi;
    App[b * 1536 + 1024 + d] = lo;
  }
  const long N1 = 3072L * 1536;
  const long N2 = N1 + 2048L * 512;
  const long N3 = N2 + 2048L * 512;
  const long N4 = N3 + 4096L * 512;
  const long N5 = N4 + 64L * 512;
  const long N6 = N5 + 64L * 1536;
  for (long idx = (long)blockIdx.x * 256 + threadIdx.x; idx < N6; idx += 2048L * 256) {
    if (idx < N1) {
      int j = (int)(idx / 1536);
      int kk = (int)(idx - (long)j * 1536);
      int k = kk & 511, seg = kk >> 9;
      const float* src = (j < 512) ? (Wh0 + (long)j * 512)
                       : (j < 1024) ? (Wc0 + (long)(j - 512) * 512)
                                    : (Wih + (long)(j - 1024) * 1024 + 512);
      float x = src[k];
      unsigned short hi = f2bf(x);
      Wcat[idx] = (seg == 1) ? (short)f2bf(x - bf2f(hi)) : (short)hi;
    } else if (idx < N2) {
      long e = idx - N1;
      Wihe[e] = (short)f2bf(Wih[(e >> 9) * 1024 + (e & 511)]);
    } else if (idx < N3) {
      long e = idx - N2;
      Whhb[e] = (short)f2bf(Whh[e]);
    } else if (idx < N4) {
      long e = idx - N3;
      int m = (int)(e >> 9), k = (int)(e & 511);
      short v = 0;
      if (m < B_ * TDEC) {
        int t = m >> 6, b = m & 63;  // t-major
        int tok = caps[b * 64 + t];
        v = (short)f2bf(emb[(long)tok * 512 + k]);
      }
      Xemb[e] = v;
    } else if (idx < N5) {
      long e = idx - N4;
      Hall[(long)B_ * TDEC * 512 + e] = 0;
    } else {
      long e = idx - N5;
      App[64L * 1536 + e] = 0;
    }
  }
}

// ---------- init GEMM: C = A(128xK) * B(NxK)^T ----------
__global__ __launch_bounds__(256) void gemm128(
    const short* __restrict__ A, const short* __restrict__ Bm, int K,
    float* __restrict__ f0, float* __restrict__ f1, float* __restrict__ f2,
    unsigned short* __restrict__ sb,
    const float* __restrict__ b0, const float* __restrict__ b1,
    const float* __restrict__ b2, const float* __restrict__ b3) {
  __shared__ short Al[4096], Bl[4096];
  const int tid = threadIdx.x, lane = tid & 63, w = tid >> 6;
  const int wr = w >> 1, wc = w & 1;
  const long n0 = (long)blockIdx.x * 128;
  f32x4 zz = {0.f, 0.f, 0.f, 0.f};
  f32x4 acc[4][4];
#pragma unroll
  for (int i = 0; i < 4; ++i)
#pragma unroll
    for (int j = 0; j < 4; ++j) acc[i][j] = zz;

  const int srow = tid >> 2, scol = (tid & 3) * 8;
  const short* Ag = A + (long)srow * K + scol;
  const short* Bg = Bm + (n0 + srow) * K + scol;
  short* Alw = &Al[w * 512];
  short* Blw = &Bl[w * 512];
  const int la = (lane & 15) * 32 + (lane >> 4) * 8;

  for (int k0 = 0; k0 < K; k0 += 32) {
    __syncthreads();
    gl16(Ag + k0, Alw);
    gl16(Ag + (long)64 * K + k0, Alw + 2048);
    gl16(Bg + k0, Blw);
    gl16(Bg + (long)64 * K + k0, Blw + 2048);
    __syncthreads();
    bf16x8 af[4], bfr[4];
#pragma unroll
    for (int mi = 0; mi < 4; ++mi) af[mi] = *(const bf16x8*)&Al[(wr * 64 + mi * 16) * 32 + la];
#pragma unroll
    for (int ni = 0; ni < 4; ++ni) bfr[ni] = *(const bf16x8*)&Bl[(wc * 64 + ni * 16) * 32 + la];
#pragma unroll
    for (int mi = 0; mi < 4; ++mi)
#pragma unroll
      for (int ni = 0; ni < 4; ++ni)
        acc[mi][ni] = __builtin_amdgcn_mfma_f32_16x16x32_bf16(af[mi], bfr[ni], acc[mi][ni], 0, 0, 0);
  }

  if (wr == 1) return;
#pragma unroll
  for (int mi = 0; mi < 4; ++mi) {
#pragma unroll
    for (int ni = 0; ni < 4; ++ni) {
      int n = (int)n0 + wc * 64 + ni * 16 + (lane & 15);
#pragma unroll
      for (int reg = 0; reg < 4; ++reg) {
        int m = mi * 16 + (lane >> 4) * 4 + reg;
        float v = acc[mi][ni][reg];
        if (n < 512) {
          float r = v * (1.f / 196.f) + b0[n];
          f0[m * 512 + n] = r;
          sb[m * 512 + n] = f2bf(r);
        } else if (n < 1024) {
          int nn = n - 512;
          float r = v * (1.f / 196.f) + b1[nn];
          f1[m * 512 + nn] = r;
        } else {
          int nn = n - 1024;
          f2[(long)nn * 64 + m] = v + b2[nn] + b3[nn];  // ENCCT[row][b]
        }
      }
    }
  }
}

// ---------- fused persistent kernel (grid 256 x 512) ----------
// Producers: per-WAVE flags (256), no in-loop __syncthreads. Wave (br,rc,wg)
// depends only on waves (br,rc',wg') — 64 flags, one per lane, polled in
// parallel. Batch-group classes have disjoint hbuf rows -> double-buffer safe.
__global__ __launch_bounds__(512, 1) void lstm_fused(
    const short* __restrict__ Whhb, const float* __restrict__ ENCCT,
    unsigned short* __restrict__ PGT, const float* __restrict__ h0f,
    const float* __restrict__ c0f, const int* __restrict__ caplen,
    unsigned short* __restrict__ hbuf, unsigned short* __restrict__ Hall,
    short* __restrict__ Wfcb, const float* __restrict__ Wfc,
    const float* __restrict__ bfc, float* __restrict__ out, int* __restrict__ flags,
    const short* __restrict__ Xemb, const short* __restrict__ Wihe) {
  __shared__ short SH[64 * 512];
  const int bid = blockIdx.x;
  const int tid = threadIdx.x, lane = tid & 63, w = tid >> 6;
  int* prog = flags + 8192;   // own line (byte 32768)
  int* mcnt = flags + 8448;   // 32 counters x 32-int stride
  int* wcnt = flags + 9600;   // own line

  if (bid == NWG) {
    // ---------------- aggregator: min over 256 wave flags -> prog ----------
    if (w != 0) return;
    int cur = 0;
    while (cur < TDEC) {
      int m = 0x7fffffff;
#pragma unroll
      for (int j = 0; j < 4; ++j) {
        int v = __hip_atomic_load(&flags[(lane * 4 + j) * 32], __ATOMIC_RELAXED,
                                  __HIP_MEMORY_SCOPE_AGENT);
        m = (v < m) ? v : m;
      }
#pragma unroll
      for (int o = 32; o; o >>= 1) {
        int t2 = __shfl_xor(m, o, 64);
        m = (t2 < m) ? t2 : m;
      }
      if (lane == 0 && m > cur)
        __hip_atomic_store(prog, m, __ATOMIC_RELAXED, __HIP_MEMORY_SCOPE_AGENT);
      cur = m;
    }
    return;
  }

  if (bid < NWG) {
    // ---------------- producer (recurrence, wave-autonomous) ----------------
    short* Wl = SH;
    const int wg = bid, d0 = wg * 16;
    const int br = w >> 1, rc = w & 1;
    const int myflag = (wg * 8 + w) * 32;

    for (int it = tid; it < 4096; it += 512) {
      int r = it >> 6, c8 = it & 63;
      int g = (r >> 3) & 3, rcc = r >> 5, dl_ = r & 7;
      int j = g * 512 + d0 + rcc * 8 + dl_;
      bf16x8 v = *(const bf16x8*)(Whhb + (long)j * 512 + c8 * 8);
      *(bf16x8*)&Wl[r * 512 + ((c8 * 8) ^ ((r & 7) << 3))] = v;
    }

    const int q = (lane >> 4) & 3, bit3 = (lane >> 3) & 1, dl = lane & 7;
    const int d = d0 + rc * 8 + dl;
    const int b0 = br * 16 + q * 4 + 2 * bit3;
    const int ji = d, jf = 512 + d, jg = 1024 + d, jo = 1536 + d;

    f32x2 ei = *(const f32x2*)(ENCCT + (long)ji * 64 + b0);
    f32x2 ef = *(const f32x2*)(ENCCT + (long)jf * 64 + b0);
    f32x2 eg = *(const f32x2*)(ENCCT + (long)jg * 64 + b0);
    f32x2 eo = *(const f32x2*)(ENCCT + (long)jo * 64 + b0);
    float c_r[2] = {c0f[b0 * 512 + d], c0f[(b0 + 1) * 512 + d]};
    float h_r[2] = {h0f[b0 * 512 + d], h0f[(b0 + 1) * 512 + d]};
    int dlen0 = caplen[b0] - 1, dlen1 = caplen[b0 + 1] - 1;
    __syncthreads();  // Wl ready (the ONLY intra-WG barrier)

    const int arow = br * 16 + (lane & 15);
    const int kgo = (lane >> 4) * 8;
    const int r0 = rc * 32 + (lane & 15), r1 = rc * 32 + 16 + (lane & 15);
    const int sw0 = (r0 & 7) << 3, sw1 = (r1 & 7) << 3;
    // this lane's poll target: wave (br, rc'=lane>>5) of WG (lane&31)
    const int* pollp = &flags[(((lane & 31) * 8) + br * 2 + (lane >> 5)) * 32];

#define WAIT_MT(mt_)                                                          \
    {                                                                         \
      int ok;                                                                 \
      do {                                                                    \
        int c = 0;                                                            \
        if (lane == 0)                                                        \
          c = __hip_atomic_load(&mcnt[(mt_) * 32], __ATOMIC_RELAXED,          \
                                __HIP_MEMORY_SCOPE_AGENT);                    \
        ok = __shfl(c, 0, 64);                                                \
      } while (ok < 16);                                                      \
    }
    WAIT_MT(0);
    int mt_ok = 0, pt = 1, mprobe = 0;
    unsigned pg0, pg1, pg2, pg3;
    ldpgt_issue(PGT + (long)ji * 64 + b0, PGT + (long)jf * 64 + b0,
                PGT + (long)jg * 64 + b0, PGT + (long)jo * 64 + b0, &mcnt[1 * 32],
                pg0, pg1, pg2, pg3, mprobe);

    for (int t = 0; t < TDEC; ++t) {
      const unsigned short* hsrc = hbuf + (t & 1) * 32768;
      union { u32x4 u[16]; bf16x8 v[16]; } av;
      ldh16_sc1(hsrc + arow * 512 + kgo, av.u);  // vmcnt(0) fences PGT+probe too
      asm volatile("" : "+v"(pg0), "+v"(pg1), "+v"(pg2), "+v"(pg3), "+v"(mprobe));
      if (mprobe >= 16 && pt > mt_ok) mt_ok = pt;

      f32x4 a0A = {0.f, 0.f, 0.f, 0.f}, a0B = a0A, a1A = a0A, a1B = a0A;
#pragma unroll
      for (int kk = 0; kk < 8; ++kk) {
        int kA = kk * 32 + kgo, kB = (kk + 8) * 32 + kgo;
        a0A = __builtin_amdgcn_mfma_f32_16x16x32_bf16(
            av.v[kk], *(const bf16x8*)&Wl[r0 * 512 + (kA ^ sw0)], a0A, 0, 0, 0);
        a1A = __builtin_amdgcn_mfma_f32_16x16x32_bf16(
            av.v[kk], *(const bf16x8*)&Wl[r1 * 512 + (kA ^ sw1)], a1A, 0, 0, 0);
        a0B = __builtin_amdgcn_mfma_f32_16x16x32_bf16(
            av.v[kk + 8], *(const bf16x8*)&Wl[r0 * 512 + (kB ^ sw0)], a0B, 0, 0, 0);
        a1B = __builtin_amdgcn_mfma_f32_16x16x32_bf16(
            av.v[kk + 8], *(const bf16x8*)&Wl[r1 * 512 + (kB ^ sw1)], a1B, 0, 0, 0);
      }
      f32x4 a0 = a0A + a0B, a1 = a1A + a1B;

      float own00 = bit3 ? a0[2] : a0[0], own01 = bit3 ? a0[3] : a0[1];
      float snd00 = bit3 ? a0[0] : a0[2], snd01 = bit3 ? a0[1] : a0[3];
      float own10 = bit3 ? a1[2] : a1[0], own11 = bit3 ? a1[3] : a1[1];
      float snd10 = bit3 ? a1[0] : a1[2], snd11 = bit3 ? a1[1] : a1[3];
      float rcv00 = __shfl_xor(snd00, 8, 64), rcv01 = __shfl_xor(snd01, 8, 64);
      float rcv10 = __shfl_xor(snd10, 8, 64), rcv11 = __shfl_xor(snd11, 8, 64);
      float iv[2], fv[2], gv[2], ov[2];
      iv[0] = bit3 ? rcv00 : own00; iv[1] = bit3 ? rcv01 : own01;
      fv[0] = bit3 ? own00 : rcv00; fv[1] = bit3 ? own01 : rcv01;
      gv[0] = bit3 ? rcv10 : own10; gv[1] = bit3 ? rcv11 : own11;
      ov[0] = bit3 ? own10 : rcv10; ov[1] = bit3 ? own11 : rcv11;

      unsigned short hall0, hall1, hs0, hs1;
#pragma unroll
      for (int r = 0; r < 2; ++r) {
        float ii = iv[r] + ei[r] + bf2f((unsigned short)(r ? (pg0 >> 16) : (pg0 & 0xffffu)));
        float ff = fv[r] + ef[r] + bf2f((unsigned short)(r ? (pg1 >> 16) : (pg1 & 0xffffu)));
        float gg = gv[r] + eg[r] + bf2f((unsigned short)(r ? (pg2 >> 16) : (pg2 & 0xffffu)));
        float oo = ov[r] + eo[r] + bf2f((unsigned short)(r ? (pg3 >> 16) : (pg3 & 0xffffu)));
        ii = sigm(ii); ff = sigm(ff); oo = sigm(oo); gg = tanh_fast(gg);
        float cn = ff * c_r[r] + ii * gg;
        float hn = oo * tanh_fast(cn);
        bool act = t < (r ? dlen1 : dlen0);
        if (act) { c_r[r] = cn; h_r[r] = hn; }
        unsigned short hb = f2bf(hn), h2 = f2bf(h_r[r]);
        if (r == 0) { hall0 = hb; hs0 = h2; } else { hall1 = hb; hs1 = h2; }
      }

      unsigned comb = (unsigned)hs0 | ((unsigned)hs1 << 16);
      unsigned nb = __shfl_xor((int)comb, 1, 64);
      unsigned comb2 = (unsigned)hall0 | ((unsigned)hall1 << 16);
      unsigned nb2 = __shfl_xor((int)comb2, 1, 64);
      unsigned q0 = (comb2 & 0xffffu) | (nb2 << 16);
      unsigned q1 = (comb2 >> 16) | (nb2 & 0xffff0000u);
      if (!(dl & 1)) {
        unsigned* hdst32 = (unsigned*)(hbuf + ((t + 1) & 1) * 32768);
        unsigned w0v = (comb & 0xffffu) | (nb << 16);
        unsigned w1v = (comb >> 16) | (nb & 0xffff0000u);
        st2_sc1(&hdst32[(b0 * 512 + d) >> 1], w0v, w1v);
      }
      asm volatile("s_waitcnt vmcnt(0)" ::: "memory");  // own h stores performed
      if (lane == 0)
        __hip_atomic_store(&flags[myflag], t + 1, __ATOMIC_RELAXED,
                           __HIP_MEMORY_SCOPE_AGENT);
      // deferred Hall[t] (fire-and-forget)
      if (!(dl & 1)) {
        unsigned* hall32 = (unsigned*)(Hall + (long)t * 32768);
        st2_sc1(&hall32[(b0 * 512 + d) >> 1], q0, q1);
      }
      if (t < TDEC - 1) {
        int nmt = (t + 1) >> 1;
        if (nmt > mt_ok) { WAIT_MT(nmt); mt_ok = nmt; }  // rare fallback
        const unsigned short* pgt1 = PGT + (long)(t + 1) * 2048 * 64;
        int pt2 = (mt_ok < 31) ? (mt_ok + 1) : 31;
        ldpgt_issue(pgt1 + (long)ji * 64 + b0, pgt1 + (long)jf * 64 + b0,
                    pgt1 + (long)jg * 64 + b0, pgt1 + (long)jo * 64 + b0,
                    &mcnt[pt2 * 32], pg0, pg1, pg2, pg3, mprobe);
        pt = pt2;
        // per-lane parallel poll of the 64 same-class producer-wave flags
        while (__hip_atomic_load(pollp, __ATOMIC_RELAXED, __HIP_MEMORY_SCOPE_AGENT) <=
               t) {
        }
      }
    }
    // epilogue: drain all stores, then final flag
    asm volatile("s_waitcnt vmcnt(0)" ::: "memory");
    if (lane == 0)
      __hip_atomic_store(&flags[myflag], TDEC, __ATOMIC_RELAXED,
                         __HIP_MEMORY_SCOPE_AGENT);
    return;
  }

  // ---------------- consumer ----------------
  {
    short* Al = SH;
    short* Bl = SH + 4096;
    const int wr = w >> 1, wc = w & 1;
    const int la = (lane & 15) * 32 + (lane >> 4) * 8;
    const int srow = tid >> 2, scol = (tid & 3) * 8;
    short* Alw = Al + w * 512;
    short* Blw = Bl + w * 512;
    const int cid = bid - NWG - 1;

    // ---- phase A: PGT tiles ----
    for (int idx = cid; idx < 512; idx += NCONS) {
      int mt = idx >> 4, nt = idx & 15;
      const short* Ag = Xemb + (long)(mt * 128 + srow) * 512 + scol;
      const short* Bg = Wihe + (long)(nt * 128 + srow) * 512 + scol;
      f32x4 zz = {0.f, 0.f, 0.f, 0.f};
      f32x4 acc[2][4];
#pragma unroll
      for (int i = 0; i < 2; ++i)
#pragma unroll
        for (int j = 0; j < 4; ++j) acc[i][j] = zz;
      for (int k0 = 0; k0 < 512; k0 += 32) {
        __syncthreads();
        gl16(Ag + k0, Alw);
        gl16(Bg + k0, Blw);
        __syncthreads();
        bf16x8 af[2], bfr[4];
#pragma unroll
        for (int mi = 0; mi < 2; ++mi)
          af[mi] = *(const bf16x8*)&Al[(wr * 32 + mi * 16) * 32 + la];
#pragma unroll
        for (int ni = 0; ni < 4; ++ni)
          bfr[ni] = *(const bf16x8*)&Bl[(wc * 64 + ni * 16) * 32 + la];
#pragma unroll
        for (int mi = 0; mi < 2; ++mi)
#pragma unroll
          for (int ni = 0; ni < 4; ++ni)
            acc[mi][ni] = __builtin_amdgcn_mfma_f32_16x16x32_bf16(af[mi], bfr[ni],
                                                                  acc[mi][ni], 0, 0, 0);
      }
#pragma unroll
      for (int mi = 0; mi < 2; ++mi) {
#pragma unroll
        for (int reg = 0; reg < 4; ++reg) {
          int m = mt * 128 + wr * 32 + mi * 16 + (lane >> 4) * 4 + reg;
          int trow = m >> 6, b = m & 63;
          if (trow < TDEC) {
#pragma unroll
            for (int ni = 0; ni < 4; ++ni) {
              int n = nt * 128 + wc * 64 + ni * 16 + (lane & 15);
              sts_sc1(PGT + ((long)trow * 2048 + n) * 64 + b, f2bf(acc[mi][ni][reg]));
            }
          }
        }
      }
      asm volatile("s_waitcnt vmcnt(0)" ::: "memory");  // PGT at L3
      __syncthreads();
      if (tid == 0)
        __hip_atomic_fetch_add(&mcnt[mt * 32], 1, __ATOMIC_RELAXED,
                               __HIP_MEMORY_SCOPE_AGENT);
    }

    // ---- phase A2: convert Wfcb (sc1 write-through) ----
    for (long e = (long)cid * 512 + tid; e < 10112L * 512; e += (long)NCONS * 512) {
      long j = e >> 9;
      unsigned short v = 0;
      if (j < V_) v = f2bf(Wfc[e]);
      sts_sc1((unsigned short*)Wfcb + e, v);
    }
    asm volatile("s_waitcnt vmcnt(0)" ::: "memory");
    __syncthreads();
    if (tid == 0)
      __hip_atomic_fetch_add(wcnt, 1, __ATOMIC_RELAXED, __HIP_MEMORY_SCOPE_AGENT);

    // ---- phase B: FC tiles ----
    for (int idx = cid; idx < NTILE_M * NTILE_N; idx += NCONS) {
      int mt = idx / NTILE_N, nt = idx - mt * NTILE_N;
      int need = 2 * (mt + 1) + 1; if (need > TDEC) need = TDEC;
      if (tid == 0) {
        while (__hip_atomic_load(wcnt, __ATOMIC_RELAXED, __HIP_MEMORY_SCOPE_AGENT) <
               NCONS)
          __builtin_amdgcn_s_sleep(4);
        while (__hip_atomic_load(prog, __ATOMIC_RELAXED, __HIP_MEMORY_SCOPE_AGENT) < need)
          __builtin_amdgcn_s_sleep(4);
        (void)__hip_atomic_load(prog, __ATOMIC_ACQUIRE, __HIP_MEMORY_SCOPE_AGENT);
      }
      __syncthreads();

      const unsigned short* Ag = Hall + (long)(mt * 128 + srow) * 512 + scol;
      const short* Bg = Wfcb + (long)(nt * 128 + srow) * 512 + scol;
      f32x4 zz = {0.f, 0.f, 0.f, 0.f};
      f32x4 acc[2][4];
#pragma unroll
      for (int i = 0; i < 2; ++i)
#pragma unroll
        for (int j = 0; j < 4; ++j) acc[i][j] = zz;

      for (int k0 = 0; k0 < 512; k0 += 32) {
        __syncthreads();
        gl16(Ag + k0, Alw);
        gl16(Bg + k0, Blw);
        __syncthreads();
        bf16x8 af[2], bfr[4];
#pragma unroll
        for (int mi = 0; mi < 2; ++mi)
          af[mi] = *(const bf16x8*)&Al[(wr * 32 + mi * 16) * 32 + la];
#pragma unroll
        for (int ni = 0; ni < 4; ++ni)
          bfr[ni] = *(const bf16x8*)&Bl[(wc * 64 + ni * 16) * 32 + la];
#pragma unroll
        for (int mi = 0; mi < 2; ++mi)
#pragma unroll
          for (int ni = 0; ni < 4; ++ni)
            acc[mi][ni] = __builtin_amdgcn_mfma_f32_16x16x32_bf16(af[mi], bfr[ni],
                                                                  acc[mi][ni], 0, 0, 0);
      }

#pragma unroll
      for (int mi = 0; mi < 2; ++mi) {
#pragma unroll
        for (int reg = 0; reg < 4; ++reg) {
          int m = mt * 128 + wr * 32 + mi * 16 + (lane >> 4) * 4 + reg;
          int trow = m >> 6, b = m & 63;
          if (trow < TDEC) {
            bool act = trow < (caplen[b] - 1);
            float* orow = out + ((long)b * TDEC + trow) * V_;
#pragma unroll
            for (int ni = 0; ni < 4; ++ni) {
              int n = nt * 128 + wc * 64 + ni * 16 + (lane & 15);
              if (n < V_) orow[n] = act ? (acc[mi][ni][reg] + bfc[n]) : 0.f;
            }
          }
        }
      }
    }
  }
}

// ---------- host ----------
extern "C" void kernel_launch(void* const* d_in, const int* in_sizes, int n_in,
                              void* d_out, int out_size, void* d_ws, size_t ws_size,
                              hipStream_t stream) {
  const float* enc = (const float*)d_in[0];
  const int* caps = (const int*)d_in[1];
  const int* clen = (const int*)d_in[2];
  const float* emb = (const float*)d_in[3];
  const float* Wih = (const float*)d_in[4];
  const float* bih = (const float*)d_in[5];
  const float* Whh = (const float*)d_in[6];
  const float* bhh = (const float*)d_in[7];
  const float* Wh0 = (const float*)d_in[8];
  const float* bh0 = (const float*)d_in[9];
  const float* Wc0 = (const float*)d_in[10];
  const float* bc0 = (const float*)d_in[11];
  const float* Wfc = (const float*)d_in[12];
  const float* bfc = (const float*)d_in[13];
  float* out = (float*)d_out;

  char* ws = (char*)d_ws;
  size_t off = 0;
  auto alloc = [&](size_t bytes) {
    void* p = ws + off;
    off = (off + bytes + 255) & ~(size_t)255;
    return p;
  };
  int* flags = (int*)alloc(49152);  // 256 wave flags | prog | mcnt | wcnt
  unsigned short* App = (unsigned short*)alloc(128L * 1536 * 2);
  short* Wcat = (short*)alloc(3072L * 1536 * 2);
  short* Wihe = (short*)alloc(2048L * 512 * 2);
  short* Whhb = (short*)alloc(2048L * 512 * 2);
  short* Wfcb = (short*)alloc(10112L * 512 * 2);
  short* Xemb = (short*)alloc(4096L * 512 * 2);
  unsigned short* PGT = (unsigned short*)alloc(63L * 2048 * 64 * 2);
  float* ENCCT = (float*)alloc(2048L * 64 * 4);
  float* h0f = (float*)alloc(64L * 512 * 4);
  float* c0f = (float*)alloc(64L * 512 * 4);
  unsigned short* hbuf = (unsigned short*)alloc(2L * 64 * 512 * 2);
  unsigned short* Hall = (unsigned short*)alloc(4096L * 512 * 2);  // t-major
  (void)ws_size; (void)in_sizes; (void)n_in; (void)out_size;

  hipMemsetAsync(flags, 0, 49152, stream);
  prep<<<2048, 256, 0, stream>>>(enc, Wh0, Wc0, Wih, Whh, emb, caps, Wcat, Wihe, Whhb,
                                 Xemb, Hall, App);
  gemm128<<<dim3(24), 256, 0, stream>>>((const short*)App, Wcat, 1536, h0f, c0f, ENCCT,
                                        hbuf, bh0, bc0, bih, bhh);
  lstm_fused<<<dim3(256), 512, 0, stream>>>(Whhb, ENCCT, PGT, h0f, c0f, clen, hbuf, Hall,
                                            Wfcb, Wfc, bfc, out, flags, Xemb, Wihe);
}

// Round 18
// 537.442 us; speedup vs baseline: 1.0619x; 1.0619x over previous
//
#include <hip/hip_runtime.h>

// ---------- small helpers ----------
typedef __attribute__((ext_vector_type(8))) short bf16x8;
typedef __attribute__((ext_vector_type(4))) float f32x4;
typedef __attribute__((ext_vector_type(2))) float f32x2;
typedef __attribute__((ext_vector_type(4))) unsigned int u32x4;

__device__ __forceinline__ unsigned short f2bf(float x) {
  union { float f; unsigned u; } v; v.f = x;
  unsigned r = v.u + 0x7fffu + ((v.u >> 16) & 1u);
  return (unsigned short)(r >> 16);
}
__device__ __forceinline__ float bf2f(unsigned short s) {
  union { unsigned u; float f; } v; v.u = ((unsigned)s) << 16;
  return v.f;
}
__device__ __forceinline__ float sigm(float x) { return 1.f / (1.f + __expf(-x)); }
__device__ __forceinline__ float tanh_fast(float x) { return 2.f * sigm(2.f * x) - 1.f; }

typedef const __attribute__((address_space(1))) void gvoid_t;
typedef __attribute__((address_space(3))) void lvoid_t;
__device__ __forceinline__ void gl16(const void* g, void* l) {
  __builtin_amdgcn_global_load_lds((gvoid_t*)g, (lvoid_t*)l, 16, 0, 0);
}

// 16 pipelined PLAIN sc1 loads (L3-fresh) in ONE asm block w/ internal wait.
__device__ __forceinline__ void ldh16_sc1(const unsigned short* p, u32x4 o[16]) {
  asm volatile(
      "global_load_dwordx4 %0, %16, off sc1\n\t"
      "global_load_dwordx4 %1, %16, off offset:64 sc1\n\t"
      "global_load_dwordx4 %2, %16, off offset:128 sc1\n\t"
      "global_load_dwordx4 %3, %16, off offset:192 sc1\n\t"
      "global_load_dwordx4 %4, %16, off offset:256 sc1\n\t"
      "global_load_dwordx4 %5, %16, off offset:320 sc1\n\t"
      "global_load_dwordx4 %6, %16, off offset:384 sc1\n\t"
      "global_load_dwordx4 %7, %16, off offset:448 sc1\n\t"
      "global_load_dwordx4 %8, %16, off offset:512 sc1\n\t"
      "global_load_dwordx4 %9, %16, off offset:576 sc1\n\t"
      "global_load_dwordx4 %10, %16, off offset:640 sc1\n\t"
      "global_load_dwordx4 %11, %16, off offset:704 sc1\n\t"
      "global_load_dwordx4 %12, %16, off offset:768 sc1\n\t"
      "global_load_dwordx4 %13, %16, off offset:832 sc1\n\t"
      "global_load_dwordx4 %14, %16, off offset:896 sc1\n\t"
      "global_load_dwordx4 %15, %16, off offset:960 sc1\n\t"
      "s_waitcnt vmcnt(0)"
      : "=&v"(o[0]), "=&v"(o[1]), "=&v"(o[2]), "=&v"(o[3]), "=&v"(o[4]),
        "=&v"(o[5]), "=&v"(o[6]), "=&v"(o[7]), "=&v"(o[8]), "=&v"(o[9]),
        "=&v"(o[10]), "=&v"(o[11]), "=&v"(o[12]), "=&v"(o[13]), "=&v"(o[14]),
        "=&v"(o[15])
      : "v"(p)
      : "memory");
}
__device__ __forceinline__ void st2_sc1(unsigned* p, unsigned v0, unsigned v1) {
  asm volatile("global_store_dword %0, %1, off sc1\n\t"
               "global_store_dword %0, %2, off offset:1024 sc1" ::"v"(p), "v"(v0),
               "v"(v1) : "memory");
}
// ISSUE-ONLY: 4 PGT loads + 1 mcnt probe, NO internal wait. Consumption is
// fenced later by ldh16's vmcnt(0) + a volatile "+v" dummy (rule #18).
__device__ __forceinline__ void ldpgt_issue(const unsigned short* p0,
                                            const unsigned short* p1,
                                            const unsigned short* p2,
                                            const unsigned short* p3, const int* pm,
                                            unsigned& o0, unsigned& o1, unsigned& o2,
                                            unsigned& o3, int& om) {
  asm volatile(
      "global_load_dword %0, %5, off sc1\n\t"
      "global_load_dword %1, %6, off sc1\n\t"
      "global_load_dword %2, %7, off sc1\n\t"
      "global_load_dword %3, %8, off sc1\n\t"
      "global_load_dword %4, %9, off sc1"
      : "=&v"(o0), "=&v"(o1), "=&v"(o2), "=&v"(o3), "=&v"(om)
      : "v"(p0), "v"(p1), "v"(p2), "v"(p3), "v"(pm)
      : "memory");
}
__device__ __forceinline__ void sts_sc1(unsigned short* p, unsigned short v) {
  asm volatile("global_store_short %0, %1, off sc1" ::"v"(p), "v"((unsigned)v)
               : "memory");
}

#define B_ 64
#define TDEC 63
#define D_ 512
#define V_ 10000
#define NWG 32
#define NCONS 223
#define NTILE_N 79
#define NTILE_M 32

// ---------- kernel 1: prep ----------
__global__ __launch_bounds__(256) void prep(
    const float* __restrict__ enc,
    const float* __restrict__ Wh0, const float* __restrict__ Wc0,
    const float* __restrict__ Wih, const float* __restrict__ Whh,
    const float* __restrict__ emb, const int* __restrict__ caps,
    short* __restrict__ Wcat, short* __restrict__ Wihe, short* __restrict__ Whhb,
    short* __restrict__ Xemb, unsigned short* __restrict__ Hall,
    unsigned short* __restrict__ App) {
  if (blockIdx.x < 128) {
    int b = blockIdx.x >> 1;
    int d = (blockIdx.x & 1) * 256 + threadIdx.x;
    const float* p = enc + (long)b * 196 * 512 + d;
    float s = 0.f;
#pragma unroll 4
    for (int i = 0; i < 196; ++i) s += p[(long)i * 512];
    unsigned short hi = f2bf(s);
    unsigned short lo = f2bf(s - bf2f(hi));
    App[b * 1536 + d] = hi;
    App[b * 1536 + 512 + d] = hi;
    App[b * 1536 + 1024 + d] = lo;
  }
  const long N1 = 3072L * 1536;
  const long N2 = N1 + 2048L * 512;
  const long N3 = N2 + 2048L * 512;
  const long N4 = N3 + 4096L * 512;
  const long N5 = N4 + 64L * 512;
  const long N6 = N5 + 64L * 1536;
  for (long idx = (long)blockIdx.x * 256 + threadIdx.x; idx < N6; idx += 2048L * 256) {
    if (idx < N1) {
      int j = (int)(idx / 1536);
      int kk = (int)(idx - (long)j * 1536);
      int k = kk & 511, seg = kk >> 9;
      const float* src = (j < 512) ? (Wh0 + (long)j * 512)
                       : (j < 1024) ? (Wc0 + (long)(j - 512) * 512)
                                    : (Wih + (long)(j - 1024) * 1024 + 512);
      float x = src[k];
      unsigned short hi = f2bf(x);
      Wcat[idx] = (seg == 1) ? (short)f2bf(x - bf2f(hi)) : (short)hi;
    } else if (idx < N2) {
      long e = idx - N1;
      Wihe[e] = (short)f2bf(Wih[(e >> 9) * 1024 + (e & 511)]);
    } else if (idx < N3) {
      long e = idx - N2;
      Whhb[e] = (short)f2bf(Whh[e]);
    } else if (idx < N4) {
      long e = idx - N3;
      int m = (int)(e >> 9), k = (int)(e & 511);
      short v = 0;
      if (m < B_ * TDEC) {
        int t = m >> 6, b = m & 63;  // t-major
        int tok = caps[b * 64 + t];
        v = (short)f2bf(emb[(long)tok * 512 + k]);
      }
      Xemb[e] = v;
    } else if (idx < N5) {
      long e = idx - N4;
      Hall[(long)B_ * TDEC * 512 + e] = 0;
    } else {
      long e = idx - N5;
      App[64L * 1536 + e] = 0;
    }
  }
}

// ---------- init GEMM: C = A(128xK) * B(NxK)^T ----------
__global__ __launch_bounds__(256) void gemm128(
    const short* __restrict__ A, const short* __restrict__ Bm, int K,
    float* __restrict__ f0, float* __restrict__ f1, float* __restrict__ f2,
    unsigned short* __restrict__ sb,
    const float* __restrict__ b0, const float* __restrict__ b1,
    const float* __restrict__ b2, const float* __restrict__ b3) {
  __shared__ short Al[4096], Bl[4096];
  const int tid = threadIdx.x, lane = tid & 63, w = tid >> 6;
  const int wr = w >> 1, wc = w & 1;
  const long n0 = (long)blockIdx.x * 128;
  f32x4 zz = {0.f, 0.f, 0.f, 0.f};
  f32x4 acc[4][4];
#pragma unroll
  for (int i = 0; i < 4; ++i)
#pragma unroll
    for (int j = 0; j < 4; ++j) acc[i][j] = zz;

  const int srow = tid >> 2, scol = (tid & 3) * 8;
  const short* Ag = A + (long)srow * K + scol;
  const short* Bg = Bm + (n0 + srow) * K + scol;
  short* Alw = &Al[w * 512];
  short* Blw = &Bl[w * 512];
  const int la = (lane & 15) * 32 + (lane >> 4) * 8;

  for (int k0 = 0; k0 < K; k0 += 32) {
    __syncthreads();
    gl16(Ag + k0, Alw);
    gl16(Ag + (long)64 * K + k0, Alw + 2048);
    gl16(Bg + k0, Blw);
    gl16(Bg + (long)64 * K + k0, Blw + 2048);
    __syncthreads();
    bf16x8 af[4], bfr[4];
#pragma unroll
    for (int mi = 0; mi < 4; ++mi) af[mi] = *(const bf16x8*)&Al[(wr * 64 + mi * 16) * 32 + la];
#pragma unroll
    for (int ni = 0; ni < 4; ++ni) bfr[ni] = *(const bf16x8*)&Bl[(wc * 64 + ni * 16) * 32 + la];
#pragma unroll
    for (int mi = 0; mi < 4; ++mi)
#pragma unroll
      for (int ni = 0; ni < 4; ++ni)
        acc[mi][ni] = __builtin_amdgcn_mfma_f32_16x16x32_bf16(af[mi], bfr[ni], acc[mi][ni], 0, 0, 0);
  }

  if (wr == 1) return;
#pragma unroll
  for (int mi = 0; mi < 4; ++mi) {
#pragma unroll
    for (int ni = 0; ni < 4; ++ni) {
      int n = (int)n0 + wc * 64 + ni * 16 + (lane & 15);
#pragma unroll
      for (int reg = 0; reg < 4; ++reg) {
        int m = mi * 16 + (lane >> 4) * 4 + reg;
        float v = acc[mi][ni][reg];
        if (n < 512) {
          float r = v * (1.f / 196.f) + b0[n];
          f0[m * 512 + n] = r;
          sb[m * 512 + n] = f2bf(r);
        } else if (n < 1024) {
          int nn = n - 512;
          float r = v * (1.f / 196.f) + b1[nn];
          f1[m * 512 + nn] = r;
        } else {
          int nn = n - 1024;
          f2[(long)nn * 64 + m] = v + b2[nn] + b3[nn];  // ENCCT[row][b]
        }
      }
    }
  }
}

// ---------- fused persistent kernel (grid 256 x 512) ----------
__global__ __launch_bounds__(512, 1) void lstm_fused(
    const short* __restrict__ Whhb, const float* __restrict__ ENCCT,
    unsigned short* __restrict__ PGT, const float* __restrict__ h0f,
    const float* __restrict__ c0f, const int* __restrict__ caplen,
    unsigned short* __restrict__ hbuf, unsigned short* __restrict__ Hall,
    short* __restrict__ Wfcb, const float* __restrict__ Wfc,
    const float* __restrict__ bfc, float* __restrict__ out, int* __restrict__ flags,
    const short* __restrict__ Xemb, const short* __restrict__ Wihe) {
  __shared__ short SH[64 * 512];
  const int bid = blockIdx.x;
  const int tid = threadIdx.x, lane = tid & 63, w = tid >> 6;
  int* prog = flags + 2048;   // own line
  int* mcnt = flags + 2304;   // 32 counters x 32-int stride
  int* wcnt = flags + 3392;   // own line

  if (bid == NWG) {
    // ---------------- aggregator (busy-poll) ----------------
    if (w != 0) return;
    int cur = 0;
    while (cur < TDEC) {
      int v = TDEC;
      if (lane < NWG)
        v = __hip_atomic_load(&flags[lane * 32], __ATOMIC_RELAXED,
                              __HIP_MEMORY_SCOPE_AGENT);
      int m = v;
#pragma unroll
      for (int o = 32; o; o >>= 1) {
        int t2 = __shfl_xor(m, o, 64);
        m = (t2 < m) ? t2 : m;
      }
      if (lane == 0 && m > cur)
        __hip_atomic_store(prog, m, __ATOMIC_RELAXED, __HIP_MEMORY_SCOPE_AGENT);
      cur = m;
    }
    return;
  }

  if (bid < NWG) {
    // ---------------- producer (recurrence) ----------------
    short* Wl = SH;
    const int wg = bid, d0 = wg * 16;
    const int br = w >> 1, rc = w & 1;

    for (int it = tid; it < 4096; it += 512) {
      int r = it >> 6, c8 = it & 63;
      int g = (r >> 3) & 3, rcc = r >> 5, dl_ = r & 7;
      int j = g * 512 + d0 + rcc * 8 + dl_;
      bf16x8 v = *(const bf16x8*)(Whhb + (long)j * 512 + c8 * 8);
      *(bf16x8*)&Wl[r * 512 + ((c8 * 8) ^ ((r & 7) << 3))] = v;
    }

    const int q = (lane >> 4) & 3, bit3 = (lane >> 3) & 1, dl = lane & 7;
    const int d = d0 + rc * 8 + dl;
    const int b0 = br * 16 + q * 4 + 2 * bit3;
    const int ji = d, jf = 512 + d, jg = 1024 + d, jo = 1536 + d;

    f32x2 ei = *(const f32x2*)(ENCCT + (long)ji * 64 + b0);
    f32x2 ef = *(const f32x2*)(ENCCT + (long)jf * 64 + b0);
    f32x2 eg = *(const f32x2*)(ENCCT + (long)jg * 64 + b0);
    f32x2 eo = *(const f32x2*)(ENCCT + (long)jo * 64 + b0);
    float c_r[2] = {c0f[b0 * 512 + d], c0f[(b0 + 1) * 512 + d]};
    float h_r[2] = {h0f[b0 * 512 + d], h0f[(b0 + 1) * 512 + d]};
    int dlen0 = caplen[b0] - 1, dlen1 = caplen[b0 + 1] - 1;
    __syncthreads();  // Wl ready

    const int arow = br * 16 + (lane & 15);
    const int kgo = (lane >> 4) * 8;
    const int r0 = rc * 32 + (lane & 15), r1 = rc * 32 + 16 + (lane & 15);
    const int sw0 = (r0 & 7) << 3, sw1 = (r1 & 7) << 3;

#define WAIT_MT(mt_)                                                          \
    {                                                                         \
      int ok;                                                                 \
      do {                                                                    \
        int c = 0;                                                            \
        if (lane == 0)                                                        \
          c = __hip_atomic_load(&mcnt[(mt_) * 32], __ATOMIC_RELAXED,          \
                                __HIP_MEMORY_SCOPE_AGENT);                    \
        ok = __shfl(c, 0, 64);                                                \
      } while (ok < 16);                                                      \
    }
    // prologue: block for tile 0, then ISSUE PGT(0) + probe(mt=1) (no wait)
    WAIT_MT(0);
    int mt_ok = 0, pt = 1, mprobe = 0;
    unsigned pg0, pg1, pg2, pg3;
    ldpgt_issue(PGT + (long)ji * 64 + b0, PGT + (long)jf * 64 + b0,
                PGT + (long)jg * 64 + b0, PGT + (long)jo * 64 + b0, &mcnt[1 * 32],
                pg0, pg1, pg2, pg3, mprobe);

    for (int t = 0; t < TDEC; ++t) {
      const unsigned short* hsrc = hbuf + (t & 1) * 32768;
      union { u32x4 u[16]; bf16x8 v[16]; } av;
      ldh16_sc1(hsrc + arow * 512 + kgo, av.u);  // vmcnt(0): also fences PGT+probe
      asm volatile("" : "+v"(pg0), "+v"(pg1), "+v"(pg2), "+v"(pg3), "+v"(mprobe));
      if (mprobe >= 16 && pt > mt_ok) mt_ok = pt;

      f32x4 a0A = {0.f, 0.f, 0.f, 0.f}, a0B = a0A, a1A = a0A, a1B = a0A;
#pragma unroll
      for (int kk = 0; kk < 8; ++kk) {
        int kA = kk * 32 + kgo, kB = (kk + 8) * 32 + kgo;
        a0A = __builtin_amdgcn_mfma_f32_16x16x32_bf16(
            av.v[kk], *(const bf16x8*)&Wl[r0 * 512 + (kA ^ sw0)], a0A, 0, 0, 0);
        a1A = __builtin_amdgcn_mfma_f32_16x16x32_bf16(
            av.v[kk], *(const bf16x8*)&Wl[r1 * 512 + (kA ^ sw1)], a1A, 0, 0, 0);
        a0B = __builtin_amdgcn_mfma_f32_16x16x32_bf16(
            av.v[kk + 8], *(const bf16x8*)&Wl[r0 * 512 + (kB ^ sw0)], a0B, 0, 0, 0);
        a1B = __builtin_amdgcn_mfma_f32_16x16x32_bf16(
            av.v[kk + 8], *(const bf16x8*)&Wl[r1 * 512 + (kB ^ sw1)], a1B, 0, 0, 0);
      }
      f32x4 a0 = a0A + a0B, a1 = a1A + a1B;

      float own00 = bit3 ? a0[2] : a0[0], own01 = bit3 ? a0[3] : a0[1];
      float snd00 = bit3 ? a0[0] : a0[2], snd01 = bit3 ? a0[1] : a0[3];
      float own10 = bit3 ? a1[2] : a1[0], own11 = bit3 ? a1[3] : a1[1];
      float snd10 = bit3 ? a1[0] : a1[2], snd11 = bit3 ? a1[1] : a1[3];
      float rcv00 = __shfl_xor(snd00, 8, 64), rcv01 = __shfl_xor(snd01, 8, 64);
      float rcv10 = __shfl_xor(snd10, 8, 64), rcv11 = __shfl_xor(snd11, 8, 64);
      float iv[2], fv[2], gv[2], ov[2];
      iv[0] = bit3 ? rcv00 : own00; iv[1] = bit3 ? rcv01 : own01;
      fv[0] = bit3 ? own00 : rcv00; fv[1] = bit3 ? own01 : rcv01;
      gv[0] = bit3 ? rcv10 : own10; gv[1] = bit3 ? rcv11 : own11;
      ov[0] = bit3 ? own10 : rcv10; ov[1] = bit3 ? own11 : rcv11;

      unsigned short hall0, hall1, hs0, hs1;
#pragma unroll
      for (int r = 0; r < 2; ++r) {
        float ii = iv[r] + ei[r] + bf2f((unsigned short)(r ? (pg0 >> 16) : (pg0 & 0xffffu)));
        float ff = fv[r] + ef[r] + bf2f((unsigned short)(r ? (pg1 >> 16) : (pg1 & 0xffffu)));
        float gg = gv[r] + eg[r] + bf2f((unsigned short)(r ? (pg2 >> 16) : (pg2 & 0xffffu)));
        float oo = ov[r] + eo[r] + bf2f((unsigned short)(r ? (pg3 >> 16) : (pg3 & 0xffffu)));
        ii = sigm(ii); ff = sigm(ff); oo = sigm(oo); gg = tanh_fast(gg);
        float cn = ff * c_r[r] + ii * gg;
        float hn = oo * tanh_fast(cn);
        bool act = t < (r ? dlen1 : dlen0);
        if (act) { c_r[r] = cn; h_r[r] = hn; }
        unsigned short hb = f2bf(hn), h2 = f2bf(h_r[r]);
        if (r == 0) { hall0 = hb; hs0 = h2; } else { hall1 = hb; hs1 = h2; }
      }

      unsigned comb = (unsigned)hs0 | ((unsigned)hs1 << 16);
      unsigned nb = __shfl_xor((int)comb, 1, 64);
      unsigned comb2 = (unsigned)hall0 | ((unsigned)hall1 << 16);
      unsigned nb2 = __shfl_xor((int)comb2, 1, 64);
      unsigned q0 = (comb2 & 0xffffu) | (nb2 << 16);
      unsigned q1 = (comb2 >> 16) | (nb2 & 0xffff0000u);
      // critical-path stores: next-h only
      if (!(dl & 1)) {
        unsigned* hdst32 = (unsigned*)(hbuf + ((t + 1) & 1) * 32768);
        unsigned w0v = (comb & 0xffffu) | (nb << 16);
        unsigned w1v = (comb >> 16) | (nb & 0xffff0000u);
        st2_sc1(&hdst32[(b0 * 512 + d) >> 1], w0v, w1v);
      }
      asm volatile("s_waitcnt vmcnt(0)" ::: "memory");  // h stores performed
      __syncthreads();
      if (tid == 0)
        __hip_atomic_store(&flags[wg * 32], t + 1, __ATOMIC_RELAXED,
                           __HIP_MEMORY_SCOPE_AGENT);
      // deferred Hall[t] (fire-and-forget; acked during poll window)
      if (!(dl & 1)) {
        unsigned* hall32 = (unsigned*)(Hall + (long)t * 32768);
        st2_sc1(&hall32[(b0 * 512 + d) >> 1], q0, q1);
      }
      if (t < TDEC - 1) {
        int nmt = (t + 1) >> 1;
        if (nmt > mt_ok) { WAIT_MT(nmt); mt_ok = nmt; }  // rare fallback
        const unsigned short* pgt1 = PGT + (long)(t + 1) * 2048 * 64;
        int pt2 = (mt_ok < 31) ? (mt_ok + 1) : 31;
        ldpgt_issue(pgt1 + (long)ji * 64 + b0, pgt1 + (long)jf * 64 + b0,
                    pgt1 + (long)jg * 64 + b0, pgt1 + (long)jo * 64 + b0,
                    &mcnt[pt2 * 32], pg0, pg1, pg2, pg3, mprobe);
        pt = pt2;
        if (w == 0 && lane < NWG) {  // busy-poll step flags
          const int* fp = &flags[lane * 32];
          while (__hip_atomic_load(fp, __ATOMIC_RELAXED, __HIP_MEMORY_SCOPE_AGENT) <= t) {
          }
        }
        __syncthreads();
      }
    }
    // epilogue: drain all stores, then final flag
    asm volatile("s_waitcnt vmcnt(0)" ::: "memory");
    __syncthreads();
    if (tid == 0)
      __hip_atomic_store(&flags[wg * 32], TDEC, __ATOMIC_RELAXED,
                         __HIP_MEMORY_SCOPE_AGENT);
    return;
  }

  // ---------------- consumer ----------------
  {
    short* Al = SH;
    short* Bl = SH + 4096;
    const int wr = w >> 1, wc = w & 1;
    const int la = (lane & 15) * 32 + (lane >> 4) * 8;
    const int srow = tid >> 2, scol = (tid & 3) * 8;
    short* Alw = Al + w * 512;
    short* Blw = Bl + w * 512;
    const int cid = bid - NWG - 1;

    // ---- phase A: PGT tiles ----
    for (int idx = cid; idx < 512; idx += NCONS) {
      int mt = idx >> 4, nt = idx & 15;
      const short* Ag = Xemb + (long)(mt * 128 + srow) * 512 + scol;
      const short* Bg = Wihe + (long)(nt * 128 + srow) * 512 + scol;
      f32x4 zz = {0.f, 0.f, 0.f, 0.f};
      f32x4 acc[2][4];
#pragma unroll
      for (int i = 0; i < 2; ++i)
#pragma unroll
        for (int j = 0; j < 4; ++j) acc[i][j] = zz;
      for (int k0 = 0; k0 < 512; k0 += 32) {
        __syncthreads();
        gl16(Ag + k0, Alw);
        gl16(Bg + k0, Blw);
        __syncthreads();
        bf16x8 af[2], bfr[4];
#pragma unroll
        for (int mi = 0; mi < 2; ++mi)
          af[mi] = *(const bf16x8*)&Al[(wr * 32 + mi * 16) * 32 + la];
#pragma unroll
        for (int ni = 0; ni < 4; ++ni)
          bfr[ni] = *(const bf16x8*)&Bl[(wc * 64 + ni * 16) * 32 + la];
#pragma unroll
        for (int mi = 0; mi < 2; ++mi)
#pragma unroll
          for (int ni = 0; ni < 4; ++ni)
            acc[mi][ni] = __builtin_amdgcn_mfma_f32_16x16x32_bf16(af[mi], bfr[ni],
                                                                  acc[mi][ni], 0, 0, 0);
      }
#pragma unroll
      for (int mi = 0; mi < 2; ++mi) {
#pragma unroll
        for (int reg = 0; reg < 4; ++reg) {
          int m = mt * 128 + wr * 32 + mi * 16 + (lane >> 4) * 4 + reg;
          int trow = m >> 6, b = m & 63;
          if (trow < TDEC) {
#pragma unroll
            for (int ni = 0; ni < 4; ++ni) {
              int n = nt * 128 + wc * 64 + ni * 16 + (lane & 15);
              sts_sc1(PGT + ((long)trow * 2048 + n) * 64 + b, f2bf(acc[mi][ni][reg]));
            }
          }
        }
      }
      asm volatile("s_waitcnt vmcnt(0)" ::: "memory");  // PGT at L3
      __syncthreads();
      if (tid == 0)
        __hip_atomic_fetch_add(&mcnt[mt * 32], 1, __ATOMIC_RELAXED,
                               __HIP_MEMORY_SCOPE_AGENT);
    }

    // ---- phase A2: convert Wfcb (sc1 write-through) ----
    for (long e = (long)cid * 512 + tid; e < 10112L * 512; e += (long)NCONS * 512) {
      long j = e >> 9;
      unsigned short v = 0;
      if (j < V_) v = f2bf(Wfc[e]);
      sts_sc1((unsigned short*)Wfcb + e, v);
    }
    asm volatile("s_waitcnt vmcnt(0)" ::: "memory");
    __syncthreads();
    if (tid == 0)
      __hip_atomic_fetch_add(wcnt, 1, __ATOMIC_RELAXED, __HIP_MEMORY_SCOPE_AGENT);

    // ---- phase B: FC tiles ----
    for (int idx = cid; idx < NTILE_M * NTILE_N; idx += NCONS) {
      int mt = idx / NTILE_N, nt = idx - mt * NTILE_N;
      int need = 2 * (mt + 1) + 1; if (need > TDEC) need = TDEC;
      if (tid == 0) {
        while (__hip_atomic_load(wcnt, __ATOMIC_RELAXED, __HIP_MEMORY_SCOPE_AGENT) <
               NCONS)
          __builtin_amdgcn_s_sleep(4);
        while (__hip_atomic_load(prog, __ATOMIC_RELAXED, __HIP_MEMORY_SCOPE_AGENT) < need)
          __builtin_amdgcn_s_sleep(4);
        (void)__hip_atomic_load(prog, __ATOMIC_ACQUIRE, __HIP_MEMORY_SCOPE_AGENT);
      }
      __syncthreads();

      const unsigned short* Ag = Hall + (long)(mt * 128 + srow) * 512 + scol;
      const short* Bg = Wfcb + (long)(nt * 128 + srow) * 512 + scol;
      f32x4 zz = {0.f, 0.f, 0.f, 0.f};
      f32x4 acc[2][4];
#pragma unroll
      for (int i = 0; i < 2; ++i)
#pragma unroll
        for (int j = 0; j < 4; ++j) acc[i][j] = zz;

      for (int k0 = 0; k0 < 512; k0 += 32) {
        __syncthreads();
        gl16(Ag + k0, Alw);
        gl16(Bg + k0, Blw);
        __syncthreads();
        bf16x8 af[2], bfr[4];
#pragma unroll
        for (int mi = 0; mi < 2; ++mi)
          af[mi] = *(const bf16x8*)&Al[(wr * 32 + mi * 16) * 32 + la];
#pragma unroll
        for (int ni = 0; ni < 4; ++ni)
          bfr[ni] = *(const bf16x8*)&Bl[(wc * 64 + ni * 16) * 32 + la];
#pragma unroll
        for (int mi = 0; mi < 2; ++mi)
#pragma unroll
          for (int ni = 0; ni < 4; ++ni)
            acc[mi][ni] = __builtin_amdgcn_mfma_f32_16x16x32_bf16(af[mi], bfr[ni],
                                                                  acc[mi][ni], 0, 0, 0);
      }

#pragma unroll
      for (int mi = 0; mi < 2; ++mi) {
#pragma unroll
        for (int reg = 0; reg < 4; ++reg) {
          int m = mt * 128 + wr * 32 + mi * 16 + (lane >> 4) * 4 + reg;
          int trow = m >> 6, b = m & 63;
          if (trow < TDEC) {
            bool act = trow < (caplen[b] - 1);
            float* orow = out + ((long)b * TDEC + trow) * V_;
#pragma unroll
            for (int ni = 0; ni < 4; ++ni) {
              int n = nt * 128 + wc * 64 + ni * 16 + (lane & 15);
              if (n < V_) orow[n] = act ? (acc[mi][ni][reg] + bfc[n]) : 0.f;
            }
          }
        }
      }
    }
  }
}

// ---------- host ----------
extern "C" void kernel_launch(void* const* d_in, const int* in_sizes, int n_in,
                              void* d_out, int out_size, void* d_ws, size_t ws_size,
                              hipStream_t stream) {
  const float* enc = (const float*)d_in[0];
  const int* caps = (const int*)d_in[1];
  const int* clen = (const int*)d_in[2];
  const float* emb = (const float*)d_in[3];
  const float* Wih = (const float*)d_in[4];
  const float* bih = (const float*)d_in[5];
  const float* Whh = (const float*)d_in[6];
  const float* bhh = (const float*)d_in[7];
  const float* Wh0 = (const float*)d_in[8];
  const float* bh0 = (const float*)d_in[9];
  const float* Wc0 = (const float*)d_in[10];
  const float* bc0 = (const float*)d_in[11];
  const float* Wfc = (const float*)d_in[12];
  const float* bfc = (const float*)d_in[13];
  float* out = (float*)d_out;

  char* ws = (char*)d_ws;
  size_t off = 0;
  auto alloc = [&](size_t bytes) {
    void* p = ws + off;
    off = (off + bytes + 255) & ~(size_t)255;
    return p;
  };
  int* flags = (int*)alloc(16384);  // step flags | prog | mcnt | wcnt
  unsigned short* App = (unsigned short*)alloc(128L * 1536 * 2);
  short* Wcat = (short*)alloc(3072L * 1536 * 2);
  short* Wihe = (short*)alloc(2048L * 512 * 2);
  short* Whhb = (short*)alloc(2048L * 512 * 2);
  short* Wfcb = (short*)alloc(10112L * 512 * 2);
  short* Xemb = (short*)alloc(4096L * 512 * 2);
  unsigned short* PGT = (unsigned short*)alloc(63L * 2048 * 64 * 2);
  float* ENCCT = (float*)alloc(2048L * 64 * 4);
  float* h0f = (float*)alloc(64L * 512 * 4);
  float* c0f = (float*)alloc(64L * 512 * 4);
  unsigned short* hbuf = (unsigned short*)alloc(2L * 64 * 512 * 2);
  unsigned short* Hall = (unsigned short*)alloc(4096L * 512 * 2);  // t-major
  (void)ws_size; (void)in_sizes; (void)n_in; (void)out_size;

  hipMemsetAsync(flags, 0, 16384, stream);
  prep<<<2048, 256, 0, stream>>>(enc, Wh0, Wc0, Wih, Whh, emb, caps, Wcat, Wihe, Whhb,
                                 Xemb, Hall, App);
  gemm128<<<dim3(24), 256, 0, stream>>>((const short*)App, Wcat, 1536, h0f, c0f, ENCCT,
                                        hbuf, bh0, bc0, bih, bhh);
  lstm_fused<<<dim3(256), 512, 0, stream>>>(Whhb, ENCCT, PGT, h0f, c0f, clen, hbuf, Hall,
                                            Wfcb, Wfc, bfc, out, flags, Xemb, Wihe);
}